// Round 2
// baseline (315.876 us; speedup 1.0000x reference)
//
#include <hip/hip_runtime.h>
#include <hip/hip_cooperative_groups.h>
#include <math.h>

namespace cg = cooperative_groups;

#define NEG_SLOPE 0.01f

// Bilinear resize of one output element idx of (4,3,R,R) from guide (4,3,512,512).
__device__ inline void resize_px(const float* __restrict__ g, float* __restrict__ out,
                                 int R, int idx) {
    int w = idx % R;
    int h = (idx / R) % R;
    int bc = idx / (R * R);
    float scale = 512.0f / (float)R;
    float ch = fmaxf((h + 0.5f) * scale - 0.5f, 0.f);
    float cw = fmaxf((w + 0.5f) * scale - 0.5f, 0.f);
    int h0 = (int)ch, w0 = (int)cw;
    int h1 = min(h0 + 1, 511), w1 = min(w0 + 1, 511);
    float fh = ch - (float)h0, fw = cw - (float)w0;
    const float* gp = g + (size_t)bc * (512 * 512);
    float v00 = gp[h0 * 512 + w0], v01 = gp[h0 * 512 + w1];
    float v10 = gp[h1 * 512 + w0], v11 = gp[h1 * 512 + w1];
    float top = v00 + (v01 - v00) * fw;
    float bot = v10 + (v11 - v10) * fw;
    out[idx] = top + (bot - top) * fh;
}

// One output pixel of fused nearest-up2 + PAC conv + activation.
// x: (4,Ci,H/2,W/2)  g: (4,3,H,W)  sw: (Co,Ci,9) in LDS  out: (4,Co,H,W)
// OOB taps contribute exactly zero (x_unf is zero-padded) -> skip.
template <int Ci, int Co, int ACT>
__device__ inline void pac_px(const float* __restrict__ x, const float* __restrict__ g,
                              const float* __restrict__ sw, float* __restrict__ out,
                              int idx, int H, int W) {
    int w = idx % W;
    int h = (idx / W) % H;
    int b = idx / (H * W);
    int Hh = H >> 1, Wh = W >> 1;
    int HW = H * W;
    const float* gb = g + (size_t)b * 3 * HW;
    float gc0 = gb[h * W + w];
    float gc1 = gb[HW + h * W + w];
    float gc2 = gb[2 * HW + h * W + w];
    float acc[Co];
#pragma unroll
    for (int co = 0; co < Co; ++co) acc[co] = 0.f;
    const float* xb = x + (size_t)b * Ci * Hh * Wh;
#pragma unroll
    for (int t = 0; t < 9; ++t) {
        int dh = t / 3 - 1, dw = t % 3 - 1;
        int hh = h + dh, ww = w + dw;
        if (hh < 0 || hh >= H || ww < 0 || ww >= W) continue;
        float d0 = gb[hh * W + ww] - gc0;
        float d1 = gb[HW + hh * W + ww] - gc1;
        float d2 = gb[2 * HW + hh * W + ww] - gc2;
        float k = __expf(-0.5f * (d0 * d0 + d1 * d1 + d2 * d2));
        const float* xp = xb + (hh >> 1) * Wh + (ww >> 1);
#pragma unroll
        for (int ci = 0; ci < Ci; ++ci) {
            float xv = xp[ci * Hh * Wh] * k;
#pragma unroll
            for (int co = 0; co < Co; ++co)
                acc[co] = fmaf(sw[(co * Ci + ci) * 9 + t], xv, acc[co]);
        }
    }
#pragma unroll
    for (int co = 0; co < Co; ++co) {
        float v = acc[co];
        if (ACT == 0) v = v >= 0.f ? v : NEG_SLOPE * v;
        else         v = 1.0f / (1.0f + __expf(-v));
        out[(size_t)(b * Co + co) * HW + h * W + w] = v;
    }
}

// Whole network in one cooperative kernel: 256 blocks x 256 threads (1 block/CU).
__global__ void __launch_bounds__(256)
pacnet_fused(const float* __restrict__ x, const float* __restrict__ guide,
             const float* __restrict__ lin_w, const float* __restrict__ lin_b,
             const float* __restrict__ w0, const float* __restrict__ w1,
             const float* __restrict__ w2, const float* __restrict__ w3,
             float* __restrict__ out, float* __restrict__ ws) {
    // workspace layout (floats)
    float* x16  = ws;                 // 4*16*32*32
    float* g64  = x16 + 65536;        // 4*3*64*64
    float* x0   = g64 + 49152;        // 4*4*64*64
    float* g128 = x0 + 65536;         // 4*3*128*128
    float* x1   = g128 + 196608;      // 4*4*128*128
    float* g256 = x1 + 262144;        // 4*3*256*256
    float* x2   = g256 + 786432;      // 4*4*256*256

    __shared__ float sw[576 + 144 + 144 + 36];
    float* sw0 = sw;
    float* sw1 = sw0 + 576;
    float* sw2 = sw1 + 144;
    float* sw3 = sw2 + 144;
    for (int i = threadIdx.x; i < 576; i += 256) sw0[i] = w0[i];
    for (int i = threadIdx.x; i < 144; i += 256) sw1[i] = w1[i];
    for (int i = threadIdx.x; i < 144; i += 256) sw2[i] = w2[i];
    for (int i = threadIdx.x; i < 36;  i += 256) sw3[i] = w3[i];

    cg::grid_group grid = cg::this_grid();
    const int tid = blockIdx.x * blockDim.x + threadIdx.x;
    const int T = gridDim.x * blockDim.x;   // 65536

    // ---- Stage A: linear+leaky (65536 outs) + all three guide resizes ----
    {
        int hw = tid & 1023, co = (tid >> 10) & 15, bb = tid >> 14;
        const float* xp = x + bb * 384 * 1024 + hw;
        const float* wp = lin_w + co * 384;
        float a0 = 0.f, a1 = 0.f, a2 = 0.f, a3 = 0.f;
        for (int ci = 0; ci < 384; ci += 4) {
            a0 = fmaf(wp[ci],     xp[(ci)     * 1024], a0);
            a1 = fmaf(wp[ci + 1], xp[(ci + 1) * 1024], a1);
            a2 = fmaf(wp[ci + 2], xp[(ci + 2) * 1024], a2);
            a3 = fmaf(wp[ci + 3], xp[(ci + 3) * 1024], a3);
        }
        float acc = lin_b[co] + ((a0 + a1) + (a2 + a3));
        x16[tid] = acc >= 0.f ? acc : NEG_SLOPE * acc;
    }
    for (int i = tid; i < 49152;  i += T) resize_px(guide, g64,  64,  i);
    for (int i = tid; i < 196608; i += T) resize_px(guide, g128, 128, i);
    for (int i = tid; i < 786432; i += T) resize_px(guide, g256, 256, i);
    grid.sync();

    // ---- Stage B: pac 16->4 @64 (16384 px) ----
    if (tid < 16384) pac_px<16, 4, 0>(x16, g64, sw0, x0, tid, 64, 64);
    grid.sync();

    // ---- Stage C: pac 4->4 @128 (65536 px) ----
    for (int i = tid; i < 65536; i += T) pac_px<4, 4, 0>(x0, g128, sw1, x1, i, 128, 128);
    grid.sync();

    // ---- Stage D: pac 4->4 @256 (262144 px) ----
    for (int i = tid; i < 262144; i += T) pac_px<4, 4, 0>(x1, g256, sw2, x2, i, 256, 256);
    grid.sync();

    // ---- Stage E: pac 4->1 @512 + sigmoid (1048576 px) ----
    for (int i = tid; i < 1048576; i += T) pac_px<4, 1, 1>(x2, guide, sw3, out, i, 512, 512);
}

extern "C" void kernel_launch(void* const* d_in, const int* in_sizes, int n_in,
                              void* d_out, int out_size, void* d_ws, size_t ws_size,
                              hipStream_t stream) {
    const float* x     = (const float*)d_in[0];
    const float* guide = (const float*)d_in[1];
    const float* lin_w = (const float*)d_in[2];
    const float* lin_b = (const float*)d_in[3];
    const float* w0    = (const float*)d_in[4];
    const float* w1    = (const float*)d_in[5];
    const float* w2    = (const float*)d_in[6];
    const float* w3    = (const float*)d_in[7];
    float* out = (float*)d_out;
    float* wsf = (float*)d_ws;

    void* args[] = {(void*)&x, (void*)&guide, (void*)&lin_w, (void*)&lin_b,
                    (void*)&w0, (void*)&w1, (void*)&w2, (void*)&w3,
                    (void*)&out, (void*)&wsf};
    dim3 grid(256), block(256);
    hipLaunchCooperativeKernel((void*)pacnet_fused, grid, block, args, 0, stream);
}

// Round 3
// 239.525 us; speedup vs baseline: 1.3188x; 1.3188x over previous
//
#include <hip/hip_runtime.h>
#include <math.h>

#define NEG_SLOPE 0.01f

// ---------------------------------------------------------------------------
// Kernel 1: 1x1 conv (16 <- 384) + bias + leaky.  x:(4,384,32,32) -> x16:(4,16,1024)
// 256 blocks x 256 threads. Block = (batch, 16 hw positions); thread = (co, hw).
// x is read exactly once; weights staged in LDS with +1 pad (no bank conflicts).
// ---------------------------------------------------------------------------
__global__ void __launch_bounds__(256)
linear_leaky_kernel(const float* __restrict__ x, const float* __restrict__ w,
                    const float* __restrict__ bias, float* __restrict__ x16g) {
    __shared__ float sw[16][385];
    __shared__ float sx[64 * 16];
    int bid = blockIdx.x;          // 256
    int bb  = bid >> 6;            // batch
    int hw0 = (bid & 63) << 4;     // 16 hw per block
    for (int i = threadIdx.x; i < 6144; i += 256) sw[i / 384][i % 384] = w[i];
    int co = threadIdx.x >> 4, hwl = threadIdx.x & 15;
    float acc = 0.f;
    const float* xb = x + bb * 384 * 1024 + hw0;
    for (int c0 = 0; c0 < 384; c0 += 64) {
        __syncthreads();
        for (int i = threadIdx.x; i < 1024; i += 256) {
            int ci = i >> 4, hl = i & 15;
            sx[i] = xb[(c0 + ci) * 1024 + hl];
        }
        __syncthreads();
#pragma unroll
        for (int ci = 0; ci < 64; ++ci)
            acc = fmaf(sw[co][c0 + ci], sx[(ci << 4) | hwl], acc);
    }
    acc += bias[co];
    acc = acc >= 0.f ? acc : NEG_SLOPE * acc;
    x16g[((bb * 16 + co) << 10) + hw0 + hwl] = acc;
}

// ---------------------------------------------------------------------------
// Bilinear sample of guide channel plane (512x512) at integer coord (r,c) of an
// RxR grid; scale = 512/R. Reference semantics: c = max((o+0.5)*scale-0.5, 0).
// ---------------------------------------------------------------------------
__device__ inline float bilin(const float* __restrict__ gp, float scale, int r, int c) {
    float ch = fmaxf((r + 0.5f) * scale - 0.5f, 0.f);
    float cw = fmaxf((c + 0.5f) * scale - 0.5f, 0.f);
    int h0 = (int)ch, w0 = (int)cw;
    int h1 = min(h0 + 1, 511), w1 = min(w0 + 1, 511);
    float fh = ch - (float)h0, fw = cw - (float)w0;
    float v00 = gp[h0 * 512 + w0], v01 = gp[h0 * 512 + w1];
    float v10 = gp[h1 * 512 + w0], v11 = gp[h1 * 512 + w1];
    float top = v00 + (v01 - v00) * fw;
    float bot = v10 + (v11 - v10) * fw;
    return top + (bot - top) * fh;
}

// ---------------------------------------------------------------------------
// In-LDS PAC stage: out[Co][NO][NO] (leaky) from x[Ci][NX][NX] + guide[3][NG][NG].
// Global coords: out rows [BOr,BOr+NO), x rows [BXr,+NX), g rows [BGr,+NG).
// OOB output slots are written 0 (never read by valid consumers); OOB taps skipped
// (their x_unf contribution is exactly zero in the reference).
// ---------------------------------------------------------------------------
template <int Ci, int Co>
__device__ inline void pac_lds(const float* __restrict__ sx, int BXr, int BXc, int NX,
                               const float* __restrict__ sg, int BGr, int BGc, int NG,
                               const float* __restrict__ sw, float* __restrict__ so,
                               int BOr, int BOc, int NO, int RES) {
    const int NG2 = NG * NG, NX2 = NX * NX, NO2 = NO * NO;
    for (int i = threadIdx.x; i < NO2; i += 256) {
        int r = i / NO, c = i % NO;
        int gh = BOr + r, gw = BOc + c;
        float acc[Co];
#pragma unroll
        for (int co = 0; co < Co; ++co) acc[co] = 0.f;
        if (gh >= 0 && gh < RES && gw >= 0 && gw < RES) {
            int lc0 = (gh - BGr) * NG + (gw - BGc);
            float gc0 = sg[lc0], gc1 = sg[NG2 + lc0], gc2 = sg[2 * NG2 + lc0];
#pragma unroll
            for (int tt = 0; tt < 9; ++tt) {
                int hh = gh + tt / 3 - 1, ww = gw + tt % 3 - 1;
                if (hh < 0 || hh >= RES || ww < 0 || ww >= RES) continue;
                int lt = (hh - BGr) * NG + (ww - BGc);
                float d0 = sg[lt] - gc0;
                float d1 = sg[NG2 + lt] - gc1;
                float d2 = sg[2 * NG2 + lt] - gc2;
                float k = __expf(-0.5f * (d0 * d0 + d1 * d1 + d2 * d2));
                int lx = ((hh >> 1) - BXr) * NX + ((ww >> 1) - BXc);
#pragma unroll
                for (int ci = 0; ci < Ci; ++ci) {
                    float xv = sx[ci * NX2 + lx] * k;
#pragma unroll
                    for (int co = 0; co < Co; ++co)
                        acc[co] = fmaf(sw[(co * Ci + ci) * 9 + tt], xv, acc[co]);
                }
            }
        }
#pragma unroll
        for (int co = 0; co < Co; ++co) {
            float v = acc[co];
            so[co * NO2 + i] = v >= 0.f ? v : NEG_SLOPE * v;
        }
    }
}

// ---------------------------------------------------------------------------
// Kernel 2: whole PAC chain per 32x32 output tile, all intermediates in LDS.
// 1024 blocks (4 batch x 16 x 16 tiles) x 256 threads, ~34 KB LDS -> 4 blk/CU.
// ---------------------------------------------------------------------------
__global__ void __launch_bounds__(256, 4)
pac_chain_kernel(const float* __restrict__ x16g, const float* __restrict__ guide,
                 const float* __restrict__ w0, const float* __restrict__ w1,
                 const float* __restrict__ w2, const float* __restrict__ w3,
                 float* __restrict__ out) {
    __shared__ float smem[8432];
    float* sw0   = smem;            // 576   (4,16,9)
    float* sw1   = sw0 + 576;       // 144   (4,4,9)
    float* sw2   = sw1 + 144;       // 144
    float* sw3   = sw2 + 144;       // 36    (1,4,9)
    float* sx16  = sw3 + 36;        // 400   [16][5][5]
    float* sg64  = sx16 + 400;      // 192   [3][8][8]
    float* sx0   = sg64 + 192;      // 144   [4][6][6]
    float* sg128 = sx0 + 144;       // 432   [3][12][12]
    float* sx1   = sg128 + 432;     // 400   [4][10][10]
    float* sg256 = sx1 + 400;       // 1200  [3][20][20]
    float* sx2   = sg256 + 1200;    // 1296  [4][18][18]
    float* sg512 = sx2 + 1296;      // 3468  [3][34][34]

    int bid = blockIdx.x;           // 1024
    int b = bid >> 8;
    int t = (bid >> 4) & 15;        // tileY
    int u = bid & 15;               // tileX

    const int BXr = 2 * t - 1,  BXc = 2 * u - 1;    // x16 (32-res), 5
    const int BG0r = 4 * t - 2, BG0c = 4 * u - 2;   // g64, 8
    const int B0r = 4 * t - 1,  B0c = 4 * u - 1;    // x0 (64-res), 6
    const int BG1r = 8 * t - 2, BG1c = 8 * u - 2;   // g128, 12
    const int B1r = 8 * t - 1,  B1c = 8 * u - 1;    // x1 (128-res), 10
    const int BG2r = 16 * t - 2, BG2c = 16 * u - 2; // g256, 20
    const int B2r = 16 * t - 1,  B2c = 16 * u - 1;  // x2 (256-res), 18
    const int BG3r = 32 * t - 1, BG3c = 32 * u - 1; // g512, 34

    const float* gb = guide + (size_t)b * 3 * 262144;

    // ---- stage all inputs ----
    for (int i = threadIdx.x; i < 576; i += 256) sw0[i] = w0[i];
    for (int i = threadIdx.x; i < 144; i += 256) sw1[i] = w1[i];
    for (int i = threadIdx.x; i < 144; i += 256) sw2[i] = w2[i];
    for (int i = threadIdx.x; i < 36;  i += 256) sw3[i] = w3[i];
    for (int i = threadIdx.x; i < 400; i += 256) {           // x16 [16][5][5]
        int ci = i / 25, rem = i % 25, r = rem / 5, c = rem % 5;
        int gr = BXr + r, gc = BXc + c;
        float v = 0.f;
        if (gr >= 0 && gr < 32 && gc >= 0 && gc < 32)
            v = x16g[((b * 16 + ci) << 10) + (gr << 5) + gc];
        sx16[i] = v;
    }
    for (int i = threadIdx.x; i < 192; i += 256) {           // g64 [3][8][8]
        int ch = i >> 6, rem = i & 63, r = rem >> 3, c = rem & 7;
        int gr = BG0r + r, gc = BG0c + c;
        float v = 0.f;
        if (gr >= 0 && gr < 64 && gc >= 0 && gc < 64)
            v = bilin(gb + ch * 262144, 8.0f, gr, gc);
        sg64[i] = v;
    }
    for (int i = threadIdx.x; i < 432; i += 256) {           // g128 [3][12][12]
        int ch = i / 144, rem = i % 144, r = rem / 12, c = rem % 12;
        int gr = BG1r + r, gc = BG1c + c;
        float v = 0.f;
        if (gr >= 0 && gr < 128 && gc >= 0 && gc < 128)
            v = bilin(gb + ch * 262144, 4.0f, gr, gc);
        sg128[i] = v;
    }
    for (int i = threadIdx.x; i < 1200; i += 256) {          // g256 [3][20][20]
        int ch = i / 400, rem = i % 400, r = rem / 20, c = rem % 20;
        int gr = BG2r + r, gc = BG2c + c;
        float v = 0.f;
        if (gr >= 0 && gr < 256 && gc >= 0 && gc < 256)
            v = bilin(gb + ch * 262144, 2.0f, gr, gc);
        sg256[i] = v;
    }
    for (int i = threadIdx.x; i < 3468; i += 256) {          // g512 [3][34][34]
        int ch = i / 1156, rem = i % 1156, r = rem / 34, c = rem % 34;
        int gr = BG3r + r, gc = BG3c + c;
        float v = 0.f;
        if (gr >= 0 && gr < 512 && gc >= 0 && gc < 512)
            v = gb[ch * 262144 + (gr << 9) + gc];
        sg512[i] = v;
    }
    __syncthreads();

    // ---- pac chain in LDS ----
    pac_lds<16, 4>(sx16, BXr, BXc, 5, sg64, BG0r, BG0c, 8, sw0, sx0, B0r, B0c, 6, 64);
    __syncthreads();
    pac_lds<4, 4>(sx0, B0r, B0c, 6, sg128, BG1r, BG1c, 12, sw1, sx1, B1r, B1c, 10, 128);
    __syncthreads();
    pac_lds<4, 4>(sx1, B1r, B1c, 10, sg256, BG2r, BG2c, 20, sw2, sx2, B2r, B2c, 18, 256);
    __syncthreads();

    // ---- final: pac 4->1 @512 + sigmoid, direct to global ----
    float* ob = out + (size_t)b * 262144;
    for (int i = threadIdx.x; i < 1024; i += 256) {
        int r = i >> 5, c = i & 31;
        int gh = 32 * t + r, gw = 32 * u + c;
        int lc0 = (gh - BG3r) * 34 + (gw - BG3c);
        float gc0 = sg512[lc0], gc1 = sg512[1156 + lc0], gc2 = sg512[2 * 1156 + lc0];
        float acc = 0.f;
#pragma unroll
        for (int tt = 0; tt < 9; ++tt) {
            int hh = gh + tt / 3 - 1, ww = gw + tt % 3 - 1;
            if (hh < 0 || hh >= 512 || ww < 0 || ww >= 512) continue;
            int lt = (hh - BG3r) * 34 + (ww - BG3c);
            float d0 = sg512[lt] - gc0;
            float d1 = sg512[1156 + lt] - gc1;
            float d2 = sg512[2 * 1156 + lt] - gc2;
            float k = __expf(-0.5f * (d0 * d0 + d1 * d1 + d2 * d2));
            int lx = ((hh >> 1) - B2r) * 18 + ((ww >> 1) - B2c);
#pragma unroll
            for (int ci = 0; ci < 4; ++ci)
                acc = fmaf(sw3[ci * 9 + tt], sx2[ci * 324 + lx] * k, acc);
        }
        ob[(gh << 9) + gw] = 1.0f / (1.0f + __expf(-acc));
    }
}

extern "C" void kernel_launch(void* const* d_in, const int* in_sizes, int n_in,
                              void* d_out, int out_size, void* d_ws, size_t ws_size,
                              hipStream_t stream) {
    const float* x     = (const float*)d_in[0];
    const float* guide = (const float*)d_in[1];
    const float* lin_w = (const float*)d_in[2];
    const float* lin_b = (const float*)d_in[3];
    const float* w0    = (const float*)d_in[4];
    const float* w1    = (const float*)d_in[5];
    const float* w2    = (const float*)d_in[6];
    const float* w3    = (const float*)d_in[7];
    float* out = (float*)d_out;
    float* x16g = (float*)d_ws;    // 4*16*32*32 floats

    linear_leaky_kernel<<<256, 256, 0, stream>>>(x, lin_w, lin_b, x16g);
    pac_chain_kernel<<<1024, 256, 0, stream>>>(x16g, guide, w0, w1, w2, w3, out);
}

// Round 4
// 223.841 us; speedup vs baseline: 1.4112x; 1.0701x over previous
//
#include <hip/hip_runtime.h>
#include <math.h>

#define NEG_SLOPE 0.01f

// ---------------------------------------------------------------------------
// Kernel 1: 1x1 conv (16 <- 384) + bias + leaky.  x:(4,384,32,32) -> x16:(4,16,1024)
// ---------------------------------------------------------------------------
__global__ void __launch_bounds__(256)
linear_leaky_kernel(const float* __restrict__ x, const float* __restrict__ w,
                    const float* __restrict__ bias, float* __restrict__ x16g) {
    __shared__ float sw[16][385];
    __shared__ float sx[64 * 16];
    int bid = blockIdx.x;          // 256
    int bb  = bid >> 6;            // batch
    int hw0 = (bid & 63) << 4;     // 16 hw per block
    for (int i = threadIdx.x; i < 6144; i += 256) sw[i / 384][i % 384] = w[i];
    int co = threadIdx.x >> 4, hwl = threadIdx.x & 15;
    float acc = 0.f;
    const float* xb = x + bb * 384 * 1024 + hw0;
    for (int c0 = 0; c0 < 384; c0 += 64) {
        __syncthreads();
        for (int i = threadIdx.x; i < 1024; i += 256) {
            int ci = i >> 4, hl = i & 15;
            sx[i] = xb[(c0 + ci) * 1024 + hl];
        }
        __syncthreads();
#pragma unroll
        for (int ci = 0; ci < 64; ++ci)
            acc = fmaf(sw[co][c0 + ci], sx[(ci << 4) | hwl], acc);
    }
    acc += bias[co];
    acc = acc >= 0.f ? acc : NEG_SLOPE * acc;
    x16g[((bb * 16 + co) << 10) + hw0 + hwl] = acc;
}

// ---------------------------------------------------------------------------
// Bilinear sample of guide channel plane (512x512) at (r,c) of an RxR grid.
// ---------------------------------------------------------------------------
__device__ inline float bilin(const float* __restrict__ gp, float scale, int r, int c) {
    float ch = fmaxf((r + 0.5f) * scale - 0.5f, 0.f);
    float cw = fmaxf((c + 0.5f) * scale - 0.5f, 0.f);
    int h0 = (int)ch, w0 = (int)cw;
    int h1 = min(h0 + 1, 511), w1 = min(w0 + 1, 511);
    float fh = ch - (float)h0, fw = cw - (float)w0;
    float v00 = gp[h0 * 512 + w0], v01 = gp[h0 * 512 + w1];
    float v10 = gp[h1 * 512 + w0], v11 = gp[h1 * 512 + w1];
    float top = v00 + (v01 - v00) * fw;
    float bot = v10 + (v11 - v10) * fw;
    return top + (bot - top) * fh;
}

// ---------------------------------------------------------------------------
// Kernel 2: precompute all three resized guide planes (coalesced, once).
// g256: 786432 px, g128: 196608 px, g64: 49152 px  -> 1032192 total = 4032*256.
// ---------------------------------------------------------------------------
__global__ void __launch_bounds__(256)
resize_all_kernel(const float* __restrict__ g, float* __restrict__ g64p,
                  float* __restrict__ g128p, float* __restrict__ g256p) {
    int idx = blockIdx.x * 256 + threadIdx.x;
    int R; float scale; float* outp; int o;
    if (idx < 786432)       { R = 256; scale = 2.f; outp = g256p; o = idx; }
    else if (idx < 983040)  { R = 128; scale = 4.f; outp = g128p; o = idx - 786432; }
    else                    { R = 64;  scale = 8.f; outp = g64p;  o = idx - 983040; }
    int c = o % R;
    int r = (o / R) % R;
    int bc = o / (R * R);
    outp[o] = bilin(g + (size_t)bc * 262144, scale, r, c);
}

// ---------------------------------------------------------------------------
// In-LDS PAC stage (identical math to the round-3 version, which passed).
// ---------------------------------------------------------------------------
template <int Ci, int Co>
__device__ inline void pac_lds(const float* __restrict__ sx, int BXr, int BXc, int NX,
                               const float* __restrict__ sg, int BGr, int BGc, int NG,
                               const float* __restrict__ sw, float* __restrict__ so,
                               int BOr, int BOc, int NO, int RES) {
    const int NG2 = NG * NG, NX2 = NX * NX, NO2 = NO * NO;
    for (int i = threadIdx.x; i < NO2; i += 256) {
        int r = i / NO, c = i % NO;
        int gh = BOr + r, gw = BOc + c;
        float acc[Co];
#pragma unroll
        for (int co = 0; co < Co; ++co) acc[co] = 0.f;
        if (gh >= 0 && gh < RES && gw >= 0 && gw < RES) {
            int lc0 = (gh - BGr) * NG + (gw - BGc);
            float gc0 = sg[lc0], gc1 = sg[NG2 + lc0], gc2 = sg[2 * NG2 + lc0];
#pragma unroll
            for (int tt = 0; tt < 9; ++tt) {
                int hh = gh + tt / 3 - 1, ww = gw + tt % 3 - 1;
                if (hh < 0 || hh >= RES || ww < 0 || ww >= RES) continue;
                int lt = (hh - BGr) * NG + (ww - BGc);
                float d0 = sg[lt] - gc0;
                float d1 = sg[NG2 + lt] - gc1;
                float d2 = sg[2 * NG2 + lt] - gc2;
                float k = __expf(-0.5f * (d0 * d0 + d1 * d1 + d2 * d2));
                int lx = ((hh >> 1) - BXr) * NX + ((ww >> 1) - BXc);
#pragma unroll
                for (int ci = 0; ci < Ci; ++ci) {
                    float xv = sx[ci * NX2 + lx] * k;
#pragma unroll
                    for (int co = 0; co < Co; ++co)
                        acc[co] = fmaf(sw[(co * Ci + ci) * 9 + tt], xv, acc[co]);
                }
            }
        }
#pragma unroll
        for (int co = 0; co < Co; ++co) {
            float v = acc[co];
            so[co * NO2 + i] = v >= 0.f ? v : NEG_SLOPE * v;
        }
    }
}

// ---------------------------------------------------------------------------
// Kernel 3: whole PAC chain per 32x32 output tile; guide levels read from the
// precomputed planes (coalesced). LDS overlay: early-stage buffers share the
// sx2 slot (disjoint lifetimes). 29.1 KB LDS -> 5 blocks/CU.
// XCD swizzle: bid&7 -> (batch, image half) so each XCD's L2 holds ~2 MB of guide.
// ---------------------------------------------------------------------------
__global__ void __launch_bounds__(256)
pac_chain_kernel(const float* __restrict__ x16g, const float* __restrict__ guide,
                 const float* __restrict__ g64p, const float* __restrict__ g128p,
                 const float* __restrict__ g256p,
                 const float* __restrict__ w0, const float* __restrict__ w1,
                 const float* __restrict__ w2, const float* __restrict__ w3,
                 float* __restrict__ out) {
    __shared__ float smem[7264];
    float* sw0   = smem;            // 576
    float* sw1   = smem + 576;      // 144
    float* sw2   = smem + 720;      // 144
    float* sw3   = smem + 864;      // 36
    float* sg512 = smem + 900;      // 3468 [3][34][34]
    float* sg256 = smem + 4368;     // 1200 [3][20][20]
    float* sx1   = smem + 5568;     // 400  [4][10][10]
    float* A     = smem + 5968;     // 1296 overlay region
    float* sg128 = A;               // 432  [3][12][12]   (dead after stage C)
    float* sx0   = A + 432;         // 144  [4][6][6]     (dead after stage C)
    float* sx16  = A + 576;         // 400  [16][5][5]    (dead after stage B)
    float* sg64  = A + 976;         // 192  [3][8][8]     (dead after stage B)
    float* sx2   = A;               // 1296 [4][18][18]   (written at stage D)

    // XCD-aware tile assignment: xcd = bid&7 -> (b, half); j = bid>>3 -> tile in half.
    int bid = blockIdx.x;           // 1024
    int xcd = bid & 7;
    int j   = bid >> 3;             // 0..127
    int b    = xcd >> 1;
    int half = xcd & 1;
    int t = half * 8 + (j >> 4);    // tileY 0..15
    int u = j & 15;                 // tileX 0..15

    const int BXr = 2 * t - 1,  BXc = 2 * u - 1;    // x16 (32-res), 5
    const int BG0r = 4 * t - 2, BG0c = 4 * u - 2;   // g64, 8
    const int B0r = 4 * t - 1,  B0c = 4 * u - 1;    // x0 (64-res), 6
    const int BG1r = 8 * t - 2, BG1c = 8 * u - 2;   // g128, 12
    const int B1r = 8 * t - 1,  B1c = 8 * u - 1;    // x1 (128-res), 10
    const int BG2r = 16 * t - 2, BG2c = 16 * u - 2; // g256, 20
    const int B2r = 16 * t - 1,  B2c = 16 * u - 1;  // x2 (256-res), 18
    const int BG3r = 32 * t - 1, BG3c = 32 * u - 1; // g512, 34

    const float* gb = guide + (size_t)b * 3 * 262144;

    // ---- stage all inputs (coalesced; largest first to get loads in flight) ----
    for (int i = threadIdx.x; i < 3468; i += 256) {          // g512 [3][34][34]
        int ch = i / 1156, rem = i % 1156, r = rem / 34, c = rem % 34;
        int gr = BG3r + r, gc = BG3c + c;
        float v = 0.f;
        if (gr >= 0 && gr < 512 && gc >= 0 && gc < 512)
            v = gb[ch * 262144 + (gr << 9) + gc];
        sg512[i] = v;
    }
    for (int i = threadIdx.x; i < 1200; i += 256) {          // g256 [3][20][20]
        int ch = i / 400, rem = i % 400, r = rem / 20, c = rem % 20;
        int gr = BG2r + r, gc = BG2c + c;
        float v = 0.f;
        if (gr >= 0 && gr < 256 && gc >= 0 && gc < 256)
            v = g256p[(b * 3 + ch) * 65536 + (gr << 8) + gc];
        sg256[i] = v;
    }
    for (int i = threadIdx.x; i < 432; i += 256) {           // g128 [3][12][12]
        int ch = i / 144, rem = i % 144, r = rem / 12, c = rem % 12;
        int gr = BG1r + r, gc = BG1c + c;
        float v = 0.f;
        if (gr >= 0 && gr < 128 && gc >= 0 && gc < 128)
            v = g128p[(b * 3 + ch) * 16384 + (gr << 7) + gc];
        sg128[i] = v;
    }
    for (int i = threadIdx.x; i < 192; i += 256) {           // g64 [3][8][8]
        int ch = i >> 6, rem = i & 63, r = rem >> 3, c = rem & 7;
        int gr = BG0r + r, gc = BG0c + c;
        float v = 0.f;
        if (gr >= 0 && gr < 64 && gc >= 0 && gc < 64)
            v = g64p[(b * 3 + ch) * 4096 + (gr << 6) + gc];
        sg64[i] = v;
    }
    for (int i = threadIdx.x; i < 400; i += 256) {           // x16 [16][5][5]
        int ci = i / 25, rem = i % 25, r = rem / 5, c = rem % 5;
        int gr = BXr + r, gc = BXc + c;
        float v = 0.f;
        if (gr >= 0 && gr < 32 && gc >= 0 && gc < 32)
            v = x16g[((b * 16 + ci) << 10) + (gr << 5) + gc];
        sx16[i] = v;
    }
    for (int i = threadIdx.x; i < 576; i += 256) sw0[i] = w0[i];
    for (int i = threadIdx.x; i < 144; i += 256) sw1[i] = w1[i];
    for (int i = threadIdx.x; i < 144; i += 256) sw2[i] = w2[i];
    for (int i = threadIdx.x; i < 36;  i += 256) sw3[i] = w3[i];
    __syncthreads();

    // ---- pac chain in LDS ----
    pac_lds<16, 4>(sx16, BXr, BXc, 5, sg64, BG0r, BG0c, 8, sw0, sx0, B0r, B0c, 6, 64);
    __syncthreads();
    pac_lds<4, 4>(sx0, B0r, B0c, 6, sg128, BG1r, BG1c, 12, sw1, sx1, B1r, B1c, 10, 128);
    __syncthreads();   // after this, A's early contents are dead; sx2 may overwrite A
    pac_lds<4, 4>(sx1, B1r, B1c, 10, sg256, BG2r, BG2c, 20, sw2, sx2, B2r, B2c, 18, 256);
    __syncthreads();

    // ---- final: pac 4->1 @512 + sigmoid, direct to global ----
    float* ob = out + (size_t)b * 262144;
    for (int i = threadIdx.x; i < 1024; i += 256) {
        int r = i >> 5, c = i & 31;
        int gh = 32 * t + r, gw = 32 * u + c;
        int lc0 = (gh - BG3r) * 34 + (gw - BG3c);
        float gc0 = sg512[lc0], gc1 = sg512[1156 + lc0], gc2 = sg512[2 * 1156 + lc0];
        float acc = 0.f;
#pragma unroll
        for (int tt = 0; tt < 9; ++tt) {
            int hh = gh + tt / 3 - 1, ww = gw + tt % 3 - 1;
            if (hh < 0 || hh >= 512 || ww < 0 || ww >= 512) continue;
            int lt = (hh - BG3r) * 34 + (ww - BG3c);
            float d0 = sg512[lt] - gc0;
            float d1 = sg512[1156 + lt] - gc1;
            float d2 = sg512[2 * 1156 + lt] - gc2;
            float k = __expf(-0.5f * (d0 * d0 + d1 * d1 + d2 * d2));
            int lx = ((hh >> 1) - B2r) * 18 + ((ww >> 1) - B2c);
#pragma unroll
            for (int ci = 0; ci < 4; ++ci)
                acc = fmaf(sw3[ci * 9 + tt], sx2[ci * 324 + lx] * k, acc);
        }
        ob[(gh << 9) + gw] = 1.0f / (1.0f + __expf(-acc));
    }
}

extern "C" void kernel_launch(void* const* d_in, const int* in_sizes, int n_in,
                              void* d_out, int out_size, void* d_ws, size_t ws_size,
                              hipStream_t stream) {
    const float* x     = (const float*)d_in[0];
    const float* guide = (const float*)d_in[1];
    const float* lin_w = (const float*)d_in[2];
    const float* lin_b = (const float*)d_in[3];
    const float* w0    = (const float*)d_in[4];
    const float* w1    = (const float*)d_in[5];
    const float* w2    = (const float*)d_in[6];
    const float* w3    = (const float*)d_in[7];
    float* out = (float*)d_out;

    float* ws    = (float*)d_ws;
    float* x16g  = ws;                 // 65536
    float* g64p  = x16g + 65536;       // 49152
    float* g128p = g64p + 49152;       // 196608
    float* g256p = g128p + 196608;     // 786432

    linear_leaky_kernel<<<256, 256, 0, stream>>>(x, lin_w, lin_b, x16g);
    resize_all_kernel<<<4032, 256, 0, stream>>>(guide, g64p, g128p, g256p);
    pac_chain_kernel<<<1024, 256, 0, stream>>>(x16g, guide, g64p, g128p, g256p,
                                               w0, w1, w2, w3, out);
}

// Round 5
// 125.546 us; speedup vs baseline: 2.5160x; 1.7829x over previous
//
#include <hip/hip_runtime.h>
#include <math.h>

#define NEG_SLOPE 0.01f

// ---------------------------------------------------------------------------
// Bilinear sample of guide channel plane (512x512) at (r,c) of an RxR grid.
// ---------------------------------------------------------------------------
__device__ inline float bilin(const float* __restrict__ gp, float scale, int r, int c) {
    float ch = fmaxf((r + 0.5f) * scale - 0.5f, 0.f);
    float cw = fmaxf((c + 0.5f) * scale - 0.5f, 0.f);
    int h0 = (int)ch, w0 = (int)cw;
    int h1 = min(h0 + 1, 511), w1 = min(w0 + 1, 511);
    float fh = ch - (float)h0, fw = cw - (float)w0;
    float v00 = gp[h0 * 512 + w0], v01 = gp[h0 * 512 + w1];
    float v10 = gp[h1 * 512 + w0], v11 = gp[h1 * 512 + w1];
    float top = v00 + (v01 - v00) * fw;
    float bot = v10 + (v11 - v10) * fw;
    return top + (bot - top) * fh;
}

// ---------------------------------------------------------------------------
// Kernel 1 (fused independent prep work):
//   blocks [0,256):    1x1 conv 16<-384 + bias + leaky  -> x16 (4,16,32,32)
//   blocks [256,4288): bilinear guide pyramids g256/g128/g64 (coalesced writes)
// ---------------------------------------------------------------------------
__global__ void __launch_bounds__(256)
prep_kernel(const float* __restrict__ x, const float* __restrict__ lw,
            const float* __restrict__ lb, float* __restrict__ x16,
            const float* __restrict__ g, float* __restrict__ g64p,
            float* __restrict__ g128p, float* __restrict__ g256p) {
    int bid = blockIdx.x;
    if (bid < 256) {
        int idx = bid * 256 + threadIdx.x;       // 65536 outputs
        int hw = idx & 1023, co = (idx >> 10) & 15, bb = idx >> 14;
        const float* xp = x + bb * 384 * 1024 + hw;
        const float* wp = lw + co * 384;
        float a0 = 0.f, a1 = 0.f, a2 = 0.f, a3 = 0.f;
        for (int ci = 0; ci < 384; ci += 4) {
            a0 = fmaf(wp[ci],     xp[(ci)     * 1024], a0);
            a1 = fmaf(wp[ci + 1], xp[(ci + 1) * 1024], a1);
            a2 = fmaf(wp[ci + 2], xp[(ci + 2) * 1024], a2);
            a3 = fmaf(wp[ci + 3], xp[(ci + 3) * 1024], a3);
        }
        float acc = lb[co] + ((a0 + a1) + (a2 + a3));
        x16[idx] = acc >= 0.f ? acc : NEG_SLOPE * acc;
    } else {
        int idx = (bid - 256) * 256 + threadIdx.x;   // 1032192 px total
        int R; float scale; float* outp; int o;
        if (idx < 786432)      { R = 256; scale = 2.f; outp = g256p; o = idx; }
        else if (idx < 983040) { R = 128; scale = 4.f; outp = g128p; o = idx - 786432; }
        else                   { R = 64;  scale = 8.f; outp = g64p;  o = idx - 983040; }
        int c = o % R;
        int r = (o / R) % R;
        int bc = o / (R * R);
        outp[o] = bilin(g + (size_t)bc * 262144, scale, r, c);
    }
}

// ---------------------------------------------------------------------------
// PAC stage: nearest-up2 (implicit h>>1 indexing) + 3x3 PAC conv + activation.
// x: (4,Ci,R/2,R/2)  g: (4,3,R,R)  wk: (Co,Ci,9)  out: (4,Co,R,R)
// One thread per output pixel; grid sized exactly to 4*R*R/256.
// OOB taps contribute exactly zero in the reference (zero-padded x_unf) -> skip.
// ACT: 0 = leaky, 1 = sigmoid.  Identical math to the round-1 kernel (passed).
// ---------------------------------------------------------------------------
template <int Ci, int Co, int R, int ACT>
__global__ void __launch_bounds__(256)
pac_stage(const float* __restrict__ x, const float* __restrict__ g,
          const float* __restrict__ wk, float* __restrict__ out) {
    __shared__ float sw[Co * Ci * 9];
    for (int i = threadIdx.x; i < Co * Ci * 9; i += 256) sw[i] = wk[i];
    __syncthreads();

    constexpr int HW = R * R;
    constexpr int Rh = R / 2;
    constexpr int HWh = Rh * Rh;
    int idx = blockIdx.x * 256 + threadIdx.x;
    int w = idx & (R - 1);
    int h = (idx / R) & (R - 1);
    int b = idx / HW;

    const float* gb = g + (size_t)b * 3 * HW;
    int ctr = h * R + w;
    float gc0 = gb[ctr];
    float gc1 = gb[HW + ctr];
    float gc2 = gb[2 * HW + ctr];

    float acc[Co];
#pragma unroll
    for (int co = 0; co < Co; ++co) acc[co] = 0.f;

    const float* xb = x + (size_t)b * Ci * HWh;

#pragma unroll
    for (int t = 0; t < 9; ++t) {
        int dh = t / 3 - 1, dw = t % 3 - 1;
        int hh = h + dh, ww = w + dw;
        if (hh < 0 || hh >= R || ww < 0 || ww >= R) continue;
        int tap = hh * R + ww;
        float d0 = gb[tap] - gc0;
        float d1 = gb[HW + tap] - gc1;
        float d2 = gb[2 * HW + tap] - gc2;
        float k = __expf(-0.5f * (d0 * d0 + d1 * d1 + d2 * d2));
        const float* xp = xb + (hh >> 1) * Rh + (ww >> 1);
#pragma unroll
        for (int ci = 0; ci < Ci; ++ci) {
            float xv = xp[ci * HWh] * k;
#pragma unroll
            for (int co = 0; co < Co; ++co)
                acc[co] = fmaf(sw[(co * Ci + ci) * 9 + t], xv, acc[co]);
        }
    }

#pragma unroll
    for (int co = 0; co < Co; ++co) {
        float v = acc[co];
        if (ACT == 0) v = v >= 0.f ? v : NEG_SLOPE * v;
        else          v = 1.0f / (1.0f + __expf(-v));
        out[(size_t)(b * Co + co) * HW + ctr] = v;
    }
}

extern "C" void kernel_launch(void* const* d_in, const int* in_sizes, int n_in,
                              void* d_out, int out_size, void* d_ws, size_t ws_size,
                              hipStream_t stream) {
    const float* x     = (const float*)d_in[0];   // (4,384,32,32)
    const float* guide = (const float*)d_in[1];   // (4,3,512,512)
    const float* lin_w = (const float*)d_in[2];   // (16,384,1,1)
    const float* lin_b = (const float*)d_in[3];   // (16,)
    const float* w0    = (const float*)d_in[4];   // (4,16,3,3)
    const float* w1    = (const float*)d_in[5];   // (4,4,3,3)
    const float* w2    = (const float*)d_in[6];   // (4,4,3,3)
    const float* w3    = (const float*)d_in[7];   // (1,4,3,3)
    float* out = (float*)d_out;                   // (4,1,512,512)

    float* ws    = (float*)d_ws;
    float* x16   = ws;                 // 65536
    float* g64p  = x16 + 65536;        // 49152   (4,3,64,64)
    float* g128p = g64p + 49152;       // 196608  (4,3,128,128)
    float* g256p = g128p + 196608;     // 786432  (4,3,256,256)
    float* x0    = g256p + 786432;     // 65536   (4,4,64,64)
    float* x1    = x0 + 65536;         // 262144  (4,4,128,128)
    float* x2    = x1 + 262144;        // 1048576 (4,4,256,256)

    prep_kernel<<<4288, 256, 0, stream>>>(x, lin_w, lin_b, x16, guide, g64p, g128p, g256p);
    pac_stage<16, 4, 64, 0><<<64, 256, 0, stream>>>(x16, g64p, w0, x0);
    pac_stage<4, 4, 128, 0><<<256, 256, 0, stream>>>(x0, g128p, w1, x1);
    pac_stage<4, 4, 256, 0><<<1024, 256, 0, stream>>>(x1, g256p, w2, x2);
    pac_stage<4, 1, 512, 1><<<4096, 256, 0, stream>>>(x2, guide, w3, out);
}